// Round 11
// baseline (480.705 us; speedup 1.0000x reference)
//
#include <hip/hip_runtime.h>
#include <math.h>

// ---------------- problem constants ----------------
constexpr int kB = 4, kW = 2000, kI = 64, kS = 64, kT = 24, kU = 32, kUS = 2;
constexpr int kPER = kW + kI + kS + kU + 1;   // 2161 nodes per graph
constexpr int kN   = kB * kPER;               // 8644 nodes total
constexpr int kTxtPer  = kW + kS + kU + 1;    // 2097 text rows per graph
constexpr int kTxtRows = kB * kTxtPer;        // 8388 text rows
constexpr int kEmb = 300;
constexpr int kEmbPad = 320;
constexpr int kHid = 1024;
constexpr int kOut = 512;
constexpr int kCap = 256;                     // max gathered rows for sparse gat2
constexpr int kMaxDeg = 256;                  // softmax LDS capacity per head
constexpr int kNcB = 1152;                    // gat B rows: 1024 f cols + 4 el + 4 er + 120 pad

typedef __attribute__((ext_vector_type(8))) short bf16x8;
typedef __attribute__((ext_vector_type(4))) float f32x4;

__device__ __forceinline__ unsigned short f2bf(float f) {
  union { float f; unsigned int u; } x; x.f = f;
  unsigned int r = x.u + 0x7FFF + ((x.u >> 16) & 1);
  return (unsigned short)(r >> 16);
}
__device__ __forceinline__ float bf2f(unsigned short u) {
  union { unsigned int u; float f; } x; x.u = ((unsigned int)u) << 16;
  return x.f;
}

// ---------------- mega prep: all independent init work in ONE launch ----------------
// segments: txW 320 | imW 2048 | g0 1024 | g1 1024 | g2 512 | imgcvt 512 |
//           sent 256 | rowmap 34 | zcnt 34 | zCimg 256 | zCg2 128 | walwar 8 | zpad 60
__global__ __launch_bounds__(256) void k_prep0(
    const float* __restrict__ tx_w, unsigned short* __restrict__ o_tx,
    const float* __restrict__ im_w, unsigned short* __restrict__ o_im,
    const float* __restrict__ g0_w, unsigned short* __restrict__ o_g0,   // [kNcB][1024]
    const float* __restrict__ g1_w, unsigned short* __restrict__ o_g1,   // [kNcB][1024]
    const float* __restrict__ g2_w, unsigned short* __restrict__ o_g2,
    const float* __restrict__ img, unsigned short* __restrict__ o_img,
    const int* __restrict__ sents, const float* __restrict__ smask,
    const float* __restrict__ wemb, float* __restrict__ sent,
    int* __restrict__ rmt, int* __restrict__ rmi,
    int* __restrict__ cnt, float* __restrict__ Cimg, float* __restrict__ Cg2,
    const float* __restrict__ g0_al, const float* __restrict__ g0_ar,
    const float* __restrict__ g1_al, const float* __restrict__ g1_ar) {
  int b = blockIdx.x;
  int tid = threadIdx.x;
  int tx = tid & 31, ty = tid >> 5;

  // ---- weight transposes ----
  const float* in = nullptr; unsigned short* out = nullptr; int K = 0, N = 0, Kpad = 0, nbx = 0;
  if (b < 320)                { in = tx_w; out = o_tx; K = kEmb; N = kHid; Kpad = kEmbPad; nbx = 32; }
  else if ((b -= 320) < 2048) { in = im_w; out = o_im; K = 2048; N = kHid; Kpad = 2048; nbx = 32; }
  else if ((b -= 2048) < 1024){ in = g0_w; out = o_g0; K = kHid; N = kHid; Kpad = kHid; nbx = 32; }
  else if ((b -= 1024) < 1024){ in = g1_w; out = o_g1; K = kHid; N = kHid; Kpad = kHid; nbx = 32; }
  else if ((b -= 1024) < 512) { in = g2_w; out = o_g2; K = kHid; N = kOut; Kpad = kHid; nbx = 16; }
  else if ((b -= 512) < 512) {
    int i = b * 1024 + tid * 4;
    float4 v = *(const float4*)(img + i);
    ushort4 o; o.x = f2bf(v.x); o.y = f2bf(v.y); o.z = f2bf(v.z); o.w = f2bf(v.w);
    *(ushort4*)(o_img + i) = o;
    return;
  } else if ((b -= 512) < 256) {
    // sentence masked mean
    __shared__ int idx[kT];
    __shared__ float mk[kT];
    __shared__ float s_cnt;
    if (tid < kT) { idx[tid] = sents[b * kT + tid]; mk[tid] = smask[b * kT + tid]; }
    __syncthreads();
    if (tid == 0) {
      float c = 0.f;
      for (int i = 0; i < kT; ++i) c += mk[i];
      s_cnt = (c == 0.f) ? 1.f : c;
    }
    __syncthreads();
    for (int d = tid; d < kEmb; d += 256) {
      float acc = 0.f;
      for (int i = 0; i < kT; ++i) acc += wemb[idx[i] * kEmb + d] * mk[i];
      sent[b * kEmb + d] = acc / s_cnt;
    }
    return;
  } else if ((b -= 256) < 34) {
    int i = b * 256 + tid;
    if (i < kTxtRows) {
      int g = i / kTxtPer, j = i - g * kTxtPer;
      int base = g * kPER;
      int node;
      if (j < kW)                 node = base + j;
      else if (j < kW + kS)       node = base + kW + kI + (j - kW);
      else if (j < kW + kS + kU)  node = base + kW + kI + kS + (j - kW - kS);
      else                        node = base + kW + kI + kS + kU;
      rmt[i] = node;
    }
    if (i < kB * kI) {
      int g = i >> 6;
      rmi[i] = g * kPER + kW + (i & 63);
    }
    return;
  } else if ((b -= 34) < 34) {
    int i = b * 256 + tid;
    if (i < kN) cnt[i] = 0;
    return;
  } else if ((b -= 34) < 256) {
    uint4 z = make_uint4(0u, 0u, 0u, 0u);
    ((uint4*)Cimg)[b * 256 + tid] = z;
    return;
  } else if ((b -= 256) < 128) {
    uint4 z = make_uint4(0u, 0u, 0u, 0u);
    ((uint4*)Cg2)[b * 256 + tid] = z;
    return;
  } else if ((b -= 128) < 8) {
    // wal/war projections: wt[1024 + which*4 + h][k] = sum_d fc[k][h*256+d] * a[h*256+d]
    int layer = b >> 2, which = (b >> 1) & 1, kslab = b & 1;
    const float* fc = layer ? g1_w : g0_w;
    const float* a  = layer ? (which ? g1_ar : g1_al) : (which ? g0_ar : g0_al);
    unsigned short* wt = layer ? o_g1 : o_g0;
    for (int k = kslab * 512 + tid; k < kslab * 512 + 512; k += 256) {
#pragma unroll
      for (int h = 0; h < 4; ++h) {
        float s = 0.f;
        for (int d = 0; d < 256; ++d) s += fc[(size_t)k * kHid + h * 256 + d] * a[h * 256 + d];
        wt[(size_t)(1024 + which * 4 + h) * kHid + k] = f2bf(s);
      }
    }
    return;
  } else {
    // zero pad rows 1032..1151 of both extended gat weights
    b -= 8;
    int i = b * 256 + tid;                 // 0..15359
    uint4 z = make_uint4(0u, 0u, 0u, 0u);
    ((uint4*)(o_g0 + (size_t)1032 * kHid))[i] = z;
    ((uint4*)(o_g1 + (size_t)1032 * kHid))[i] = z;
    return;
  }

  // transpose body (reached only for the 5 transpose segments)
  int bx = b % nbx, by = b / nbx;
  __shared__ float t[32][33];
  int n = bx * 32 + tx;
#pragma unroll
  for (int j = 0; j < 4; ++j) {
    int k = by * 32 + ty + j * 8;
    t[ty + j * 8][tx] = (k < K) ? in[(size_t)k * N + n] : 0.f;
  }
  __syncthreads();
#pragma unroll
  for (int j = 0; j < 4; ++j) {
    int nn = bx * 32 + ty + j * 8;
    int kk = by * 32 + tx;
    out[(size_t)nn * Kpad + kk] = f2bf(t[tx][ty + j * 8]);
  }
}

// ---------------- utt + sess (sess recomputed from sent) ----------------
__global__ __launch_bounds__(256) void k_utt_sess(const int* __restrict__ utts,
                                                  const float* __restrict__ umask,
                                                  const float* __restrict__ sent,
                                                  float* __restrict__ utt,
                                                  float* __restrict__ sess) {
  int blk = blockIdx.x;
  int tid = threadIdx.x;
  if (blk < kB * kU) {
    int bu = blk, b = bu / kU;
    __shared__ int idx[kUS];
    __shared__ float mk[kUS];
    __shared__ float s_cnt;
    if (tid < kUS) { idx[tid] = utts[bu * kUS + tid]; mk[tid] = umask[bu * kUS + tid]; }
    __syncthreads();
    if (tid == 0) {
      float c = 0.f;
      for (int i = 0; i < kUS; ++i) c += mk[i];
      s_cnt = (c == 0.f) ? 1.f : c;
    }
    __syncthreads();
    for (int d = tid; d < kEmb; d += 256) {
      float acc = 0.f;
      for (int i = 0; i < kUS; ++i) acc += sent[(b * kS + idx[i]) * kEmb + d] * mk[i];
      utt[bu * kEmb + d] = acc / s_cnt;
    }
  } else {
    int b = blk - kB * kU;                // graph index
    for (int d = tid; d < kEmb; d += 256) {
      float acc = 0.f;
      for (int u = 0; u < kU; ++u) {
        float ua = 0.f, c = 0.f;
        for (int us = 0; us < kUS; ++us) {
          int i = (b * kU + u) * kUS + us;
          int sidx = utts[i];
          float m = umask[i];
          ua += sent[(b * kS + sidx) * kEmb + d] * m;
          c += m;
        }
        if (c == 0.f) c = 1.f;
        acc += ua / c;
      }
      sess[b * kEmb + d] = acc * (1.f / kU);
    }
  }
}

// ---------------- txt gather (bf16) + edge count fused ----------------
__global__ __launch_bounds__(256) void k_txtcount(const int* __restrict__ aw,
                                                  const float* __restrict__ wemb,
                                                  const float* __restrict__ sent,
                                                  const float* __restrict__ utt,
                                                  const float* __restrict__ sess,
                                                  unsigned short* __restrict__ txt,
                                                  const int* __restrict__ dst,
                                                  int* __restrict__ cnt, int E) {
  int blk = blockIdx.x;
  int tid = threadIdx.x;
  if (blk < kTxtRows) {
    int r = blk;
    int g = r / kTxtPer, j = r - g * kTxtPer;
    const float* src;
    if (j < kW)                 src = wemb + (size_t)aw[g * kW + j] * kEmb;
    else if (j < kW + kS)       src = sent + (size_t)(g * kS + (j - kW)) * kEmb;
    else if (j < kW + kS + kU)  src = utt  + (size_t)(g * kU + (j - kW - kS)) * kEmb;
    else                        src = sess + (size_t)g * kEmb;
    for (int d = tid; d < kEmbPad; d += 256)
      txt[(size_t)r * kEmbPad + d] = (d < kEmb) ? f2bf(src[d]) : (unsigned short)0;
  } else {
    int e = (blk - kTxtRows) * 256 + tid;
    if (e < E) atomicAdd(&cnt[dst[e]], 1);
  }
}

// ---------------- bf16 MFMA GEMM, XCD-banded 1-D grid, optional el/er cols ----------------
// 128x128 tile, 4 waves, XOR-swizzled LDS. B has NcB rows; f output has NcOut cols.
// If ELR: B rows [NcOut, NcOut+4) are wal (-> el), [NcOut+4, NcOut+8) are war (-> er).
template <bool OBF, bool ELR>
__global__ __launch_bounds__(256) void k_mm2(const unsigned short* __restrict__ A,
                                             const unsigned short* __restrict__ Bt,
                                             const float* __restrict__ bias,
                                             const int* __restrict__ rmap,
                                             void* __restrict__ Cout,
                                             float* __restrict__ el,
                                             float* __restrict__ er,
                                             int M, int K, int NcB, int NcOut) {
  __shared__ __align__(16) unsigned short As[128 * 64];
  __shared__ __align__(16) unsigned short Bs[128 * 64];
  int nCol = NcB >> 7;
  int bi = blockIdx.x;
  int xcd = bi & 7, bj = bi >> 3;
  int colTile = bj % nCol;
  int rowTile = ((bj / nCol) << 3) + xcd;
  int row0 = rowTile << 7;
  if (row0 >= M) return;
  int col0 = colTile << 7;

  int tid = threadIdx.x;
  int wid = tid >> 6, lane = tid & 63, quad = lane >> 4, l16 = lane & 15;
  int wm = wid >> 1, wn = wid & 1;

  f32x4 acc[4][4];
  f32x4 zero4 = {0.f, 0.f, 0.f, 0.f};
#pragma unroll
  for (int i = 0; i < 4; ++i)
#pragma unroll
    for (int j = 0; j < 4; ++j) acc[i][j] = zero4;

  int ar_ = tid >> 3;       // 0..31
  int ac = tid & 7;         // 16B chunk index

  for (int k0 = 0; k0 < K; k0 += 64) {
    __syncthreads();
#pragma unroll
    for (int i = 0; i < 4; ++i) {
      int r = ar_ + i * 32;
      int sw = ((ac ^ (r & 7)) << 3);
      int grow = row0 + r;
      uint4 va = make_uint4(0u, 0u, 0u, 0u);
      if (grow < M) va = *(const uint4*)(A + (size_t)grow * K + k0 + ac * 8);
      *(uint4*)&As[r * 64 + sw] = va;
      int nrow = col0 + r;
      uint4 vb = *(const uint4*)(Bt + (size_t)nrow * K + k0 + ac * 8);
      *(uint4*)&Bs[r * 64 + sw] = vb;
    }
    __syncthreads();
#pragma unroll
    for (int s = 0; s < 2; ++s) {
      int cc = s * 4 + quad;
      bf16x8 aF[4], bF[4];
#pragma unroll
      for (int mi = 0; mi < 4; ++mi) {
        int r = wm * 64 + mi * 16 + l16;
        aF[mi] = *(const bf16x8*)&As[r * 64 + ((cc ^ (r & 7)) << 3)];
      }
#pragma unroll
      for (int ni = 0; ni < 4; ++ni) {
        int r = wn * 64 + ni * 16 + l16;
        bF[ni] = *(const bf16x8*)&Bs[r * 64 + ((cc ^ (r & 7)) << 3)];
      }
#pragma unroll
      for (int mi = 0; mi < 4; ++mi)
#pragma unroll
        for (int ni = 0; ni < 4; ++ni)
          acc[mi][ni] = __builtin_amdgcn_mfma_f32_16x16x32_bf16(aF[mi], bF[ni], acc[mi][ni], 0, 0, 0);
    }
  }

  // ---- epilogue (C/D layout: col=lane&15, row=quad*4+reg) ----
#pragma unroll
  for (int mi = 0; mi < 4; ++mi) {
#pragma unroll
    for (int ni = 0; ni < 4; ++ni) {
      int gm0 = row0 + wm * 64 + mi * 16 + quad * 4;
      int gn  = col0 + wn * 64 + ni * 16 + l16;
      float bv = (bias && gn < NcOut) ? bias[gn] : 0.f;
#pragma unroll
      for (int i = 0; i < 4; ++i) {
        int r = gm0 + i;
        if (r >= M) continue;
        float v = acc[mi][ni][i] + bv;
        if (gn < NcOut) {
          if (OBF) {
            int orow = rmap ? rmap[r] : r;
            ((unsigned short*)Cout)[(size_t)orow * NcOut + gn] = f2bf(v);
          } else {
            ((float*)Cout)[(size_t)r * NcOut + gn] = v;
          }
        } else if (ELR) {
          int gn2 = gn - NcOut;
          if (gn2 < 4)      el[r * 4 + gn2] = v;
          else if (gn2 < 8) er[r * 4 + gn2 - 4] = v;
        }
      }
    }
  }
}

// ---------------- split-K bf16 MFMA GEMM (64x64 tile, optional A-row gather) ----------------
__global__ __launch_bounds__(256) void k_mm_sk(const unsigned short* __restrict__ A,
                                               const unsigned short* __restrict__ Bt,
                                               const int* __restrict__ rowlist,
                                               float* __restrict__ C,
                                               int M, int K, int Nc, int Kc) {
  __shared__ __align__(16) unsigned short As[64 * 64];
  __shared__ __align__(16) unsigned short Bs[64 * 64];
  int tid = threadIdx.x;
  int wid = tid >> 6, lane = tid & 63, quad = lane >> 4, l16 = lane & 15;
  int row0 = blockIdx.y * 64, col0 = blockIdx.x * 64;
  int k0 = blockIdx.z * Kc;
  int k1 = k0 + Kc; if (k1 > K) k1 = K;

  f32x4 acc[4];
  f32x4 zero4 = {0.f, 0.f, 0.f, 0.f};
#pragma unroll
  for (int i = 0; i < 4; ++i) acc[i] = zero4;

  int ar_ = tid >> 3;
  int ac = tid & 7;

  for (int kk = k0; kk < k1; kk += 64) {
    __syncthreads();
#pragma unroll
    for (int i = 0; i < 2; ++i) {
      int r = ar_ + i * 32;
      int sw = ((ac ^ (r & 7)) << 3);
      int grow = row0 + r;
      uint4 va = make_uint4(0u, 0u, 0u, 0u);
      if (grow < M) {
        int arow = rowlist ? rowlist[grow] : grow;
        va = *(const uint4*)(A + (size_t)arow * K + kk + ac * 8);
      }
      *(uint4*)&As[r * 64 + sw] = va;
      int nrow = col0 + r;
      uint4 vb = *(const uint4*)(Bt + (size_t)nrow * K + kk + ac * 8);
      *(uint4*)&Bs[r * 64 + sw] = vb;
    }
    __syncthreads();
#pragma unroll
    for (int s = 0; s < 2; ++s) {
      int cc = s * 4 + quad;
      bf16x8 bF;
      {
        int r = wid * 16 + l16;
        bF = *(const bf16x8*)&Bs[r * 64 + ((cc ^ (r & 7)) << 3)];
      }
#pragma unroll
      for (int mi = 0; mi < 4; ++mi) {
        int r = mi * 16 + l16;
        bf16x8 aF = *(const bf16x8*)&As[r * 64 + ((cc ^ (r & 7)) << 3)];
        acc[mi] = __builtin_amdgcn_mfma_f32_16x16x32_bf16(aF, bF, acc[mi], 0, 0, 0);
      }
    }
  }
#pragma unroll
  for (int mi = 0; mi < 4; ++mi) {
#pragma unroll
    for (int i = 0; i < 4; ++i) {
      int r = row0 + mi * 16 + quad * 4 + i;
      int c = col0 + wid * 16 + l16;
      if (r < M) atomicAdd(&C[(size_t)r * Nc + c], acc[mi][i]);
    }
  }
}

__global__ void k_sk_epi(const float* __restrict__ Cw, const float* __restrict__ bias,
                         const int* __restrict__ rmap, unsigned short* __restrict__ out,
                         int M, int Nc) {
  int i = blockIdx.x * blockDim.x + threadIdx.x;
  if (i >= M * Nc) return;
  int r = i / Nc, c = i - r * Nc;
  out[(size_t)rmap[r] * Nc + c] = f2bf(Cw[i] + bias[c]);
}

// ---------------- CSR build ----------------
__global__ void k_scan(int* __restrict__ deg, int* __restrict__ offs, int n) {
  __shared__ int part[1024];
  int tid = threadIdx.x;
  int per = (n + 1023) >> 10;
  int start = tid * per;
  int local = 0;
  for (int i = 0; i < per; ++i) { int idx = start + i; if (idx < n) local += deg[idx]; }
  part[tid] = local;
  __syncthreads();
  for (int off = 1; off < 1024; off <<= 1) {
    int add = (tid >= off) ? part[tid - off] : 0;
    __syncthreads();
    part[tid] += add;
    __syncthreads();
  }
  int run = (tid == 0) ? 0 : part[tid - 1];
  for (int i = 0; i < per; ++i) {
    int idx = start + i;
    if (idx < n) { offs[idx] = run; run += deg[idx]; }
  }
  if (tid == 1023) offs[n] = part[1023];
  __syncthreads();
  // zero deg (used as cursor by k_fill) — saves a memset launch
  for (int i = tid; i < n; i += 1024) deg[i] = 0;
}

__global__ void k_fill(const int* __restrict__ src, const int* __restrict__ dst,
                       const int* __restrict__ offs, int* __restrict__ cur,
                       int* __restrict__ csr, int E) {
  int e = blockIdx.x * blockDim.x + threadIdx.x;
  if (e < E) {
    int d = dst[e];
    int slot = offs[d] + atomicAdd(&cur[d], 1);
    csr[slot] = src[e];
  }
}

// ---------------- fused softmax + aggregation (H=4, D=256, ELU, bf16 in/out) ----------------
__global__ __launch_bounds__(256) void k_agg3(const unsigned short* __restrict__ f,
                                              const float* __restrict__ el,
                                              const float* __restrict__ er,
                                              const int* __restrict__ offs,
                                              const int* __restrict__ csr,
                                              const float* __restrict__ bias,
                                              unsigned short* __restrict__ out) {
  __shared__ float xs[4][kMaxDeg];
  int v = blockIdx.x;
  int tid = threadIdx.x;
  int h = tid >> 6, lane = tid & 63;
  int e0 = offs[v];
  int deg = offs[v + 1] - e0;
  if (deg > kMaxDeg) deg = kMaxDeg;

  float erv = er[v * 4 + h];
  float m = -1e30f;
  for (int base = 0; base < deg; base += 64) {
    int idx = base + lane;
    float x = -1e30f;
    if (idx < deg) {
      int s = csr[e0 + idx];
      x = el[s * 4 + h] + erv;
      x = x > 0.f ? x : 0.2f * x;
      xs[h][idx] = x;
    }
    float mm = x;
#pragma unroll
    for (int o = 32; o; o >>= 1) mm = fmaxf(mm, __shfl_xor(mm, o));
    m = fmaxf(m, mm);
  }
  float zs = 0.f;
  for (int base = 0; base < deg; base += 64) {
    int idx = base + lane;
    if (idx < deg) {
      float w = expf(xs[h][idx] - m);
      xs[h][idx] = w;
      zs += w;
    }
  }
#pragma unroll
  for (int o = 32; o; o >>= 1) zs += __shfl_xor(zs, o);
  float rz = 1.f / zs;
  for (int base = 0; base < deg; base += 64) {
    int idx = base + lane;
    if (idx < deg) xs[h][idx] *= rz;
  }
  __syncthreads();

  int d0 = tid * 4;
  float a0 = 0.f, a1 = 0.f, a2 = 0.f, a3 = 0.f;
  for (int e = 0; e < deg; ++e) {
    int s = csr[e0 + e];
    float w = xs[h][e];
    ushort4 fv = *(const ushort4*)(f + (size_t)s * 1024 + d0);
    a0 += w * bf2f(fv.x);
    a1 += w * bf2f(fv.y);
    a2 += w * bf2f(fv.z);
    a3 += w * bf2f(fv.w);
  }
  float4 bv = *(const float4*)(bias + d0);
  float o0 = a0 + bv.x, o1 = a1 + bv.y, o2 = a2 + bv.z, o3 = a3 + bv.w;
  o0 = o0 > 0.f ? o0 : expm1f(o0);
  o1 = o1 > 0.f ? o1 : expm1f(o1);
  o2 = o2 > 0.f ? o2 : expm1f(o2);
  o3 = o3 > 0.f ? o3 : expm1f(o3);
  ushort4 ov;
  ov.x = f2bf(o0); ov.y = f2bf(o1); ov.z = f2bf(o2); ov.w = f2bf(o3);
  *(ushort4*)(out + (size_t)v * 1024 + d0) = ov;
}

// ---------------- sparse gat2 helpers ----------------
__global__ void k_rows2(const int* __restrict__ sid, const int* __restrict__ offs,
                        const int* __restrict__ csr, int* __restrict__ rowlist,
                        int* __restrict__ info) {
  __shared__ int degs[kB], starts[kB], total;
  int tid = threadIdx.x;
  int bv = tid >> 6, lane = tid & 63;
  if (tid < kB) {
    int v = sid[tid];
    degs[tid] = offs[v + 1] - offs[v];
  }
  __syncthreads();
  if (tid == 0) {
    int p = 0;
    for (int b = 0; b < kB; ++b) {
      starts[b] = p;
      int d = degs[b];
      if (p + d > kCap) d = kCap - p;
      degs[b] = d;
      p += d;
    }
    total = p;
  }
  __syncthreads();
  int v = sid[bv];
  int e0 = offs[v];
  int deg = degs[bv];
  int start = starts[bv];
  if (lane == 0) {
    info[bv] = start;
    info[4 + bv] = deg;
    info[8 + bv] = start;
  }
  __syncthreads();
  for (int idx = lane; idx < deg; idx += 64) {
    int s = csr[e0 + idx];
    rowlist[start + idx] = s;
    if (s == v) info[8 + bv] = start + idx;
  }
  for (int i = total + tid; i < kCap; i += 256) rowlist[i] = 0;
}

__global__ void k_elr_c(const float* __restrict__ fc, const float* __restrict__ al,
                        const float* __restrict__ ar, float* __restrict__ el,
                        float* __restrict__ er) {
  int r = blockIdx.x;
  int lane = threadIdx.x;
  float a = 0.f, b = 0.f;
  for (int d = lane * 4; d < 512; d += 256) {
    float4 x = *(const float4*)(fc + (size_t)r * 512 + d);
    float4 av = *(const float4*)(al + d);
    float4 rv = *(const float4*)(ar + d);
    a += x.x * av.x + x.y * av.y + x.z * av.z + x.w * av.w;
    b += x.x * rv.x + x.y * rv.y + x.z * rv.z + x.w * rv.w;
  }
#pragma unroll
  for (int off = 32; off; off >>= 1) {
    a += __shfl_down(a, off);
    b += __shfl_down(b, off);
  }
  if (lane == 0) { el[r] = a; er[r] = b; }
}

__global__ __launch_bounds__(256) void k_agg_fin2(const float* __restrict__ fc,
                                                  const float* __restrict__ el,
                                                  const float* __restrict__ er,
                                                  const int* __restrict__ info,
                                                  const float* __restrict__ bias,
                                                  float* __restrict__ out) {
  int bv = blockIdx.x;
  int tid = threadIdx.x;
  int start = info[bv], cnt = info[4 + bv];
  float erv = er[info[8 + bv]];
  float m = -1e30f;
  for (int i = 0; i < cnt; ++i) {
    float x = el[start + i] + erv;
    x = x > 0.f ? x : 0.2f * x;
    m = fmaxf(m, x);
  }
  float z = 0.f, a0 = 0.f, a1 = 0.f;
  for (int i = 0; i < cnt; ++i) {
    int r = start + i;
    float x = el[r] + erv;
    x = x > 0.f ? x : 0.2f * x;
    float w = expf(x - m);
    z += w;
    a0 += w * fc[(size_t)r * 512 + tid];
    a1 += w * fc[(size_t)r * 512 + 256 + tid];
  }
  out[bv * 512 + tid] = a0 / z + bias[tid];
  out[bv * 512 + 256 + tid] = a1 / z + bias[256 + tid];
}

// ---------------- launcher ----------------
extern "C" void kernel_launch(void* const* d_in, const int* in_sizes, int n_in,
                              void* d_out, int out_size, void* d_ws, size_t ws_size,
                              hipStream_t stream) {
  const int*   all_words   = (const int*)d_in[0];
  const float* image_feats = (const float*)d_in[1];
  const int*   sentences   = (const int*)d_in[2];
  const float* sent_mask   = (const float*)d_in[3];
  const int*   utterances  = (const int*)d_in[4];
  const float* utt_mask    = (const float*)d_in[5];
  const int*   session_ids = (const int*)d_in[6];
  const int*   edge_src    = (const int*)d_in[7];
  const int*   edge_dst    = (const int*)d_in[8];
  const float* word_embed  = (const float*)d_in[9];
  const float* text_fc_w   = (const float*)d_in[10];
  const float* text_fc_b   = (const float*)d_in[11];
  const float* image_fc_w  = (const float*)d_in[12];
  const float* image_fc_b  = (const float*)d_in[13];
  const float* gat0_fc     = (const float*)d_in[14];
  const float* gat0_al     = (const float*)d_in[15];
  const float* gat0_ar     = (const float*)d_in[16];
  const float* gat0_b      = (const float*)d_in[17];
  const float* gat1_fc     = (const float*)d_in[18];
  const float* gat1_al     = (const float*)d_in[19];
  const float* gat1_ar     = (const float*)d_in[20];
  const float* gat1_b      = (const float*)d_in[21];
  const float* gat2_fc     = (const float*)d_in[22];
  const float* gat2_al     = (const float*)d_in[23];
  const float* gat2_ar     = (const float*)d_in[24];
  const float* gat2_b      = (const float*)d_in[25];

  const int E = in_sizes[7];

  char* base = (char*)d_ws;
  size_t off = 0;
  auto alloc = [&](size_t elems, size_t esz) -> void* {
    void* p = base + off;
    off += ((elems * esz + 255) / 256) * 256;
    return p;
  };
  unsigned short* Abf   = (unsigned short*)alloc((size_t)kN * kHid, 2);
  unsigned short* fbf   = (unsigned short*)alloc((size_t)kN * kHid, 2);
  unsigned short* txtbf = (unsigned short*)alloc((size_t)kTxtRows * kEmbPad, 2);
  unsigned short* imgbf = (unsigned short*)alloc((size_t)kB * kI * 2048, 2);
  unsigned short* wtTx  = (unsigned short*)alloc((size_t)kHid * kEmbPad, 2);
  unsigned short* wtIm  = (unsigned short*)alloc((size_t)kHid * 2048, 2);
  unsigned short* wtG0  = (unsigned short*)alloc((size_t)kNcB * kHid, 2);   // extended
  unsigned short* wtG1  = (unsigned short*)alloc((size_t)kNcB * kHid, 2);   // extended
  unsigned short* wtG2  = (unsigned short*)alloc((size_t)kOut * kHid, 2);
  float* Cimg   = (float*)alloc((size_t)kB * kI * kHid, 4);
  float* Cg2    = (float*)alloc((size_t)kCap * kOut, 4);
  float* sentb  = (float*)alloc((size_t)kB * kS * kEmb, 4);
  float* uttb   = (float*)alloc((size_t)kB * kU * kEmb, 4);
  float* sessb  = (float*)alloc((size_t)kB * kEmb, 4);
  float* el     = (float*)alloc((size_t)kN * 4, 4);
  float* er     = (float*)alloc((size_t)kN * 4, 4);
  int*   offs   = (int*)alloc(kN + 1, 4);
  int*   cnt    = (int*)alloc(kN, 4);
  int*   csr    = (int*)alloc(E, 4);
  int*   rmt    = (int*)alloc(kTxtRows, 4);
  int*   rmi    = (int*)alloc(kB * kI, 4);
  int*   rowl   = (int*)alloc(kCap, 4);
  int*   info   = (int*)alloc(16, 4);
  (void)ws_size; (void)n_in; (void)out_size;

  // 1) mega prep: transposes, wal/war, img cvt, sent, rowmap, zeroing
  constexpr int kPrepBlocks = 320 + 2048 + 1024 + 1024 + 512 + 512 + 256 + 34 + 34 + 256 + 128 + 8 + 60;
  k_prep0<<<kPrepBlocks, 256, 0, stream>>>(
      text_fc_w, wtTx, image_fc_w, wtIm, gat0_fc, wtG0, gat1_fc, wtG1, gat2_fc, wtG2,
      image_feats, imgbf, sentences, sent_mask, word_embed, sentb, rmt, rmi,
      cnt, Cimg, Cg2, gat0_al, gat0_ar, gat1_al, gat1_ar);

  // 2) utt + sess
  k_utt_sess<<<kB * kU + kB, 256, 0, stream>>>(utterances, utt_mask, sentb, uttb, sessb);

  // 3) txt gather + edge count
  k_txtcount<<<kTxtRows + (E + 255) / 256, 256, 0, stream>>>(
      all_words, word_embed, sentb, uttb, sessb, txtbf, edge_dst, cnt, E);

  // 4) scan (also re-zeros cnt)   5) fill
  k_scan<<<1, 1024, 0, stream>>>(cnt, offs, kN);
  k_fill<<<(E + 255) / 256, 256, 0, stream>>>(edge_src, edge_dst, offs, cnt, csr, E);

  auto mmGrid = [](int M, int NcB_) {
    int nrt = (M + 127) / 128;
    return 8 * (NcB_ / 128) * ((nrt + 7) / 8);
  };

  // 6) text FC
  k_mm2<true, false><<<mmGrid(kTxtRows, kHid), 256, 0, stream>>>(
      txtbf, wtTx, text_fc_b, rmt, Abf, nullptr, nullptr, kTxtRows, kEmbPad, kHid, kHid);

  // 7-8) image FC via split-K
  k_mm_sk<<<dim3(kHid / 64, kB * kI / 64, 4), 256, 0, stream>>>(
      imgbf, wtIm, nullptr, Cimg, kB * kI, 2048, kHid, 512);
  k_sk_epi<<<(kB * kI * kHid + 255) / 256, 256, 0, stream>>>(
      Cimg, image_fc_b, rmi, Abf, kB * kI, kHid);

  // 9-10) GAT layer 0 (GEMM with fused el/er cols) + aggregation
  k_mm2<true, true><<<mmGrid(kN, kNcB), 256, 0, stream>>>(
      Abf, wtG0, nullptr, nullptr, fbf, el, er, kN, kHid, kNcB, kHid);
  k_agg3<<<kN, 256, 0, stream>>>(fbf, el, er, offs, csr, gat0_b, Abf);

  // 11-12) GAT layer 1
  k_mm2<true, true><<<mmGrid(kN, kNcB), 256, 0, stream>>>(
      Abf, wtG1, nullptr, nullptr, fbf, el, er, kN, kHid, kNcB, kHid);
  k_agg3<<<kN, 256, 0, stream>>>(fbf, el, er, offs, csr, gat1_b, Abf);

  // 13-16) GAT layer 2, sparse
  k_rows2<<<1, 256, 0, stream>>>(session_ids, offs, csr, rowl, info);
  k_mm_sk<<<dim3(kOut / 64, kCap / 64, 4), 256, 0, stream>>>(
      Abf, wtG2, rowl, Cg2, kCap, kHid, kOut, 256);
  k_elr_c<<<kCap, 64, 0, stream>>>(Cg2, gat2_al, gat2_ar, el, er);
  k_agg_fin2<<<kB, 256, 0, stream>>>(Cg2, el, er, info, gat2_b, (float*)d_out);
}

// Round 14
// 441.042 us; speedup vs baseline: 1.0899x; 1.0899x over previous
//
#include <hip/hip_runtime.h>
#include <math.h>

// ---------------- problem constants ----------------
constexpr int kB = 4, kW = 2000, kI = 64, kS = 64, kT = 24, kU = 32, kUS = 2;
constexpr int kPER = kW + kI + kS + kU + 1;   // 2161 nodes per graph
constexpr int kN   = kB * kPER;               // 8644 nodes total
constexpr int kTxtPer  = kW + kS + kU + 1;    // 2097 text rows per graph
constexpr int kTxtRows = kB * kTxtPer;        // 8388 text rows
constexpr int kEmb = 300;
constexpr int kEmbPad = 320;
constexpr int kHid = 1024;
constexpr int kOut = 512;
constexpr int kCap = 256;                     // max gathered rows for sparse gat2
constexpr int kMaxDeg = 256;                  // softmax LDS capacity per head
constexpr int kNcB = 1152;                    // gat B rows: 1024 f cols + 4 el + 4 er + 120 pad

typedef __attribute__((ext_vector_type(8))) short bf16x8;
typedef __attribute__((ext_vector_type(4))) float f32x4;

__device__ __forceinline__ unsigned short f2bf(float f) {
  union { float f; unsigned int u; } x; x.f = f;
  unsigned int r = x.u + 0x7FFF + ((x.u >> 16) & 1);
  return (unsigned short)(r >> 16);
}
__device__ __forceinline__ float bf2f(unsigned short u) {
  union { unsigned int u; float f; } x; x.u = ((unsigned int)u) << 16;
  return x.f;
}

// ---------------- mega prep (round-11-proven structure, NO wal/war segment) ----------------
// segments: txW 320 | imW 2048 | g0 1024 | g1 1024 | g2 512 | imgcvt 512 |
//           sent 256 | rowmap 34 | zcnt 34 | zCimg 256 | zCg2 128 | zpad 60
__global__ __launch_bounds__(256) void k_prep0(
    const float* __restrict__ tx_w, unsigned short* __restrict__ o_tx,
    const float* __restrict__ im_w, unsigned short* __restrict__ o_im,
    const float* __restrict__ g0_w, unsigned short* __restrict__ o_g0,   // [kNcB][1024]
    const float* __restrict__ g1_w, unsigned short* __restrict__ o_g1,   // [kNcB][1024]
    const float* __restrict__ g2_w, unsigned short* __restrict__ o_g2,
    const float* __restrict__ img, unsigned short* __restrict__ o_img,
    const int* __restrict__ sents, const float* __restrict__ smask,
    const float* __restrict__ wemb, float* __restrict__ sent,
    int* __restrict__ rmt, int* __restrict__ rmi,
    int* __restrict__ cnt, float* __restrict__ Cimg, float* __restrict__ Cg2) {
  int b = blockIdx.x;
  int tid = threadIdx.x;
  int tx = tid & 31, ty = tid >> 5;

  const float* in = nullptr; unsigned short* out = nullptr; int K = 0, N = 0, Kpad = 0, nbx = 0;
  if (b < 320)                { in = tx_w; out = o_tx; K = kEmb; N = kHid; Kpad = kEmbPad; nbx = 32; }
  else if ((b -= 320) < 2048) { in = im_w; out = o_im; K = 2048; N = kHid; Kpad = 2048; nbx = 32; }
  else if ((b -= 2048) < 1024){ in = g0_w; out = o_g0; K = kHid; N = kHid; Kpad = kHid; nbx = 32; }
  else if ((b -= 1024) < 1024){ in = g1_w; out = o_g1; K = kHid; N = kHid; Kpad = kHid; nbx = 32; }
  else if ((b -= 1024) < 512) { in = g2_w; out = o_g2; K = kHid; N = kOut; Kpad = kHid; nbx = 16; }
  else if ((b -= 512) < 512) {
    int i = b * 1024 + tid * 4;
    float4 v = *(const float4*)(img + i);
    ushort4 o; o.x = f2bf(v.x); o.y = f2bf(v.y); o.z = f2bf(v.z); o.w = f2bf(v.w);
    *(ushort4*)(o_img + i) = o;
    return;
  } else if ((b -= 512) < 256) {
    // sentence masked mean
    __shared__ int idx[kT];
    __shared__ float mk[kT];
    __shared__ float s_cnt;
    if (tid < kT) { idx[tid] = sents[b * kT + tid]; mk[tid] = smask[b * kT + tid]; }
    __syncthreads();
    if (tid == 0) {
      float c = 0.f;
      for (int i = 0; i < kT; ++i) c += mk[i];
      s_cnt = (c == 0.f) ? 1.f : c;
    }
    __syncthreads();
    for (int d = tid; d < kEmb; d += 256) {
      float acc = 0.f;
      for (int i = 0; i < kT; ++i) acc += wemb[idx[i] * kEmb + d] * mk[i];
      sent[b * kEmb + d] = acc / s_cnt;
    }
    return;
  } else if ((b -= 256) < 34) {
    int i = b * 256 + tid;
    if (i < kTxtRows) {
      int g = i / kTxtPer, j = i - g * kTxtPer;
      int base = g * kPER;
      int node;
      if (j < kW)                 node = base + j;
      else if (j < kW + kS)       node = base + kW + kI + (j - kW);
      else if (j < kW + kS + kU)  node = base + kW + kI + kS + (j - kW - kS);
      else                        node = base + kW + kI + kS + kU;
      rmt[i] = node;
    }
    if (i < kB * kI) {
      int g = i >> 6;
      rmi[i] = g * kPER + kW + (i & 63);
    }
    return;
  } else if ((b -= 34) < 34) {
    int i = b * 256 + tid;
    if (i < kN) cnt[i] = 0;
    return;
  } else if ((b -= 34) < 256) {
    uint4 z = make_uint4(0u, 0u, 0u, 0u);
    ((uint4*)Cimg)[b * 256 + tid] = z;
    return;
  } else if ((b -= 256) < 128) {
    uint4 z = make_uint4(0u, 0u, 0u, 0u);
    ((uint4*)Cg2)[b * 256 + tid] = z;
    return;
  } else {
    // zero pad rows 1032..1151 of both extended gat weights (60 blocks)
    b -= 128;
    int i = b * 256 + tid;                 // 0..15359
    uint4 z = make_uint4(0u, 0u, 0u, 0u);
    ((uint4*)(o_g0 + (size_t)1032 * kHid))[i] = z;
    ((uint4*)(o_g1 + (size_t)1032 * kHid))[i] = z;
    return;
  }

  // transpose body (reached only for the 5 transpose segments)
  int bx = b % nbx, by = b / nbx;
  __shared__ float t[32][33];
  int n = bx * 32 + tx;
#pragma unroll
  for (int j = 0; j < 4; ++j) {
    int k = by * 32 + ty + j * 8;
    t[ty + j * 8][tx] = (k < K) ? in[(size_t)k * N + n] : 0.f;
  }
  __syncthreads();
#pragma unroll
  for (int j = 0; j < 4; ++j) {
    int nn = bx * 32 + ty + j * 8;
    int kk = by * 32 + tx;
    out[(size_t)nn * Kpad + kk] = f2bf(t[tx][ty + j * 8]);
  }
}

// ---------------- utt + sess + wal/war (parallel, off critical path) ----------------
// blocks: [0, kB*kU) utt | [kB*kU, kB*kU+kB) sess | [132, 132+256) wal/war
__global__ __launch_bounds__(256) void k_utt_sess(const int* __restrict__ utts,
                                                  const float* __restrict__ umask,
                                                  const float* __restrict__ sent,
                                                  float* __restrict__ utt,
                                                  float* __restrict__ sess,
                                                  const float* __restrict__ g0_w,
                                                  const float* __restrict__ g1_w,
                                                  const float* __restrict__ g0_al,
                                                  const float* __restrict__ g0_ar,
                                                  const float* __restrict__ g1_al,
                                                  const float* __restrict__ g1_ar,
                                                  unsigned short* __restrict__ o_g0,
                                                  unsigned short* __restrict__ o_g1) {
  int blk = blockIdx.x;
  int tid = threadIdx.x;
  if (blk < kB * kU) {
    int bu = blk, b = bu / kU;
    __shared__ int idx[kUS];
    __shared__ float mk[kUS];
    __shared__ float s_cnt;
    if (tid < kUS) { idx[tid] = utts[bu * kUS + tid]; mk[tid] = umask[bu * kUS + tid]; }
    __syncthreads();
    if (tid == 0) {
      float c = 0.f;
      for (int i = 0; i < kUS; ++i) c += mk[i];
      s_cnt = (c == 0.f) ? 1.f : c;
    }
    __syncthreads();
    for (int d = tid; d < kEmb; d += 256) {
      float acc = 0.f;
      for (int i = 0; i < kUS; ++i) acc += sent[(b * kS + idx[i]) * kEmb + d] * mk[i];
      utt[bu * kEmb + d] = acc / s_cnt;
    }
  } else if (blk < kB * kU + kB) {
    int b = blk - kB * kU;                // graph index
    for (int d = tid; d < kEmb; d += 256) {
      float acc = 0.f;
      for (int u = 0; u < kU; ++u) {
        float ua = 0.f, c = 0.f;
        for (int us = 0; us < kUS; ++us) {
          int i = (b * kU + u) * kUS + us;
          int sidx = utts[i];
          float m = umask[i];
          ua += sent[(b * kS + sidx) * kEmb + d] * m;
          c += m;
        }
        if (c == 0.f) c = 1.f;
        acc += ua / c;
      }
      sess[b * kEmb + d] = acc * (1.f / kU);
    }
  } else {
    // wal/war projections: 256 blocks, each handles 64 k's of one (layer,which,head,kblk).
    // wt[1024 + which*4 + h][k] = sum_d fc[k][h*256+d] * a[h*256+d]
    int b = blk - (kB * kU + kB);         // 0..255
    int layer = b >> 7, rem = b & 127;
    int which = rem >> 6;
    int rem2 = rem & 63;
    int h = rem2 >> 4, kblk = rem2 & 15;
    const float* fc = layer ? g1_w : g0_w;
    const float* a  = layer ? (which ? g1_ar : g1_al) : (which ? g0_ar : g0_al);
    unsigned short* wt = layer ? o_g1 : o_g0;
    int kl = tid >> 2, q = tid & 3;       // 64 k's per block, 4 threads per k
    int k = kblk * 64 + kl;
    float s = 0.f;
    const float* fr = fc + (size_t)k * kHid + h * 256 + q * 64;
    const float* av = a + h * 256 + q * 64;
    for (int d = 0; d < 64; ++d) s += fr[d] * av[d];
    s += __shfl_xor(s, 1);
    s += __shfl_xor(s, 2);
    if (q == 0) wt[(size_t)(1024 + which * 4 + h) * kHid + k] = f2bf(s);
  }
}

// ---------------- txt gather (bf16) + edge count fused ----------------
__global__ __launch_bounds__(256) void k_txtcount(const int* __restrict__ aw,
                                                  const float* __restrict__ wemb,
                                                  const float* __restrict__ sent,
                                                  const float* __restrict__ utt,
                                                  const float* __restrict__ sess,
                                                  unsigned short* __restrict__ txt,
                                                  const int* __restrict__ dst,
                                                  int* __restrict__ cnt, int E) {
  int blk = blockIdx.x;
  int tid = threadIdx.x;
  if (blk < kTxtRows) {
    int r = blk;
    int g = r / kTxtPer, j = r - g * kTxtPer;
    const float* src;
    if (j < kW)                 src = wemb + (size_t)aw[g * kW + j] * kEmb;
    else if (j < kW + kS)       src = sent + (size_t)(g * kS + (j - kW)) * kEmb;
    else if (j < kW + kS + kU)  src = utt  + (size_t)(g * kU + (j - kW - kS)) * kEmb;
    else                        src = sess + (size_t)g * kEmb;
    for (int d = tid; d < kEmbPad; d += 256)
      txt[(size_t)r * kEmbPad + d] = (d < kEmb) ? f2bf(src[d]) : (unsigned short)0;
  } else {
    int e = (blk - kTxtRows) * 256 + tid;
    if (e < E) atomicAdd(&cnt[dst[e]], 1);
  }
}

// ---------------- bf16 MFMA GEMM, XCD-banded 1-D grid, optional el/er cols ----------------
template <bool OBF, bool ELR>
__global__ __launch_bounds__(256) void k_mm2(const unsigned short* __restrict__ A,
                                             const unsigned short* __restrict__ Bt,
                                             const float* __restrict__ bias,
                                             const int* __restrict__ rmap,
                                             void* __restrict__ Cout,
                                             float* __restrict__ el,
                                             float* __restrict__ er,
                                             int M, int K, int NcB, int NcOut) {
  __shared__ __align__(16) unsigned short As[128 * 64];
  __shared__ __align__(16) unsigned short Bs[128 * 64];
  int nCol = NcB >> 7;
  int bi = blockIdx.x;
  int xcd = bi & 7, bj = bi >> 3;
  int colTile = bj % nCol;
  int rowTile = ((bj / nCol) << 3) + xcd;
  int row0 = rowTile << 7;
  if (row0 >= M) return;
  int col0 = colTile << 7;

  int tid = threadIdx.x;
  int wid = tid >> 6, lane = tid & 63, quad = lane >> 4, l16 = lane & 15;
  int wm = wid >> 1, wn = wid & 1;

  f32x4 acc[4][4];
  f32x4 zero4 = {0.f, 0.f, 0.f, 0.f};
#pragma unroll
  for (int i = 0; i < 4; ++i)
#pragma unroll
    for (int j = 0; j < 4; ++j) acc[i][j] = zero4;

  int ar_ = tid >> 3;       // 0..31
  int ac = tid & 7;         // 16B chunk index

  for (int k0 = 0; k0 < K; k0 += 64) {
    __syncthreads();
#pragma unroll
    for (int i = 0; i < 4; ++i) {
      int r = ar_ + i * 32;
      int sw = ((ac ^ (r & 7)) << 3);
      int grow = row0 + r;
      uint4 va = make_uint4(0u, 0u, 0u, 0u);
      if (grow < M) va = *(const uint4*)(A + (size_t)grow * K + k0 + ac * 8);
      *(uint4*)&As[r * 64 + sw] = va;
      int nrow = col0 + r;
      uint4 vb = *(const uint4*)(Bt + (size_t)nrow * K + k0 + ac * 8);
      *(uint4*)&Bs[r * 64 + sw] = vb;
    }
    __syncthreads();
#pragma unroll
    for (int s = 0; s < 2; ++s) {
      int cc = s * 4 + quad;
      bf16x8 aF[4], bF[4];
#pragma unroll
      for (int mi = 0; mi < 4; ++mi) {
        int r = wm * 64 + mi * 16 + l16;
        aF[mi] = *(const bf16x8*)&As[r * 64 + ((cc ^ (r & 7)) << 3)];
      }
#pragma unroll
      for (int ni = 0; ni < 4; ++ni) {
        int r = wn * 64 + ni * 16 + l16;
        bF[ni] = *(const bf16x8*)&Bs[r * 64 + ((cc ^ (r & 7)) << 3)];
      }
#pragma unroll
      for (int mi = 0; mi < 4; ++mi)
#pragma unroll
        for (int ni = 0; ni < 4; ++ni)
          acc[mi][ni] = __builtin_amdgcn_mfma_f32_16x16x32_bf16(aF[mi], bF[ni], acc[mi][ni], 0, 0, 0);
    }
  }

  // ---- epilogue (C/D layout: col=lane&15, row=quad*4+reg) ----
#pragma unroll
  for (int mi = 0; mi < 4; ++mi) {
#pragma unroll
    for (int ni = 0; ni < 4; ++ni) {
      int gm0 = row0 + wm * 64 + mi * 16 + quad * 4;
      int gn  = col0 + wn * 64 + ni * 16 + l16;
      float bv = (bias && gn < NcOut) ? bias[gn] : 0.f;
#pragma unroll
      for (int i = 0; i < 4; ++i) {
        int r = gm0 + i;
        if (r >= M) continue;
        float v = acc[mi][ni][i] + bv;
        if (gn < NcOut) {
          if (OBF) {
            int orow = rmap ? rmap[r] : r;
            ((unsigned short*)Cout)[(size_t)orow * NcOut + gn] = f2bf(v);
          } else {
            ((float*)Cout)[(size_t)r * NcOut + gn] = v;
          }
        } else if (ELR) {
          int gn2 = gn - NcOut;
          if (gn2 < 4)      el[r * 4 + gn2] = v;
          else if (gn2 < 8) er[r * 4 + gn2 - 4] = v;
        }
      }
    }
  }
}

// ---------------- split-K bf16 MFMA GEMM (64x64 tile, optional A-row gather) ----------------
__global__ __launch_bounds__(256) void k_mm_sk(const unsigned short* __restrict__ A,
                                               const unsigned short* __restrict__ Bt,
                                               const int* __restrict__ rowlist,
                                               float* __restrict__ C,
                                               int M, int K, int Nc, int Kc) {
  __shared__ __align__(16) unsigned short As[64 * 64];
  __shared__ __align__(16) unsigned short Bs[64 * 64];
  int tid = threadIdx.x;
  int wid = tid >> 6, lane = tid & 63, quad = lane >> 4, l16 = lane & 15;
  int row0 = blockIdx.y * 64, col0 = blockIdx.x * 64;
  int k0 = blockIdx.z * Kc;
  int k1 = k0 + Kc; if (k1 > K) k1 = K;

  f32x4 acc[4];
  f32x4 zero4 = {0.f, 0.f, 0.f, 0.f};
#pragma unroll
  for (int i = 0; i < 4; ++i) acc[i] = zero4;

  int ar_ = tid >> 3;
  int ac = tid & 7;

  for (int kk = k0; kk < k1; kk += 64) {
    __syncthreads();
#pragma unroll
    for (int i = 0; i < 2; ++i) {
      int r = ar_ + i * 32;
      int sw = ((ac ^ (r & 7)) << 3);
      int grow = row0 + r;
      uint4 va = make_uint4(0u, 0u, 0u, 0u);
      if (grow < M) {
        int arow = rowlist ? rowlist[grow] : grow;
        va = *(const uint4*)(A + (size_t)arow * K + kk + ac * 8);
      }
      *(uint4*)&As[r * 64 + sw] = va;
      int nrow = col0 + r;
      uint4 vb = *(const uint4*)(Bt + (size_t)nrow * K + kk + ac * 8);
      *(uint4*)&Bs[r * 64 + sw] = vb;
    }
    __syncthreads();
#pragma unroll
    for (int s = 0; s < 2; ++s) {
      int cc = s * 4 + quad;
      bf16x8 bF;
      {
        int r = wid * 16 + l16;
        bF = *(const bf16x8*)&Bs[r * 64 + ((cc ^ (r & 7)) << 3)];
      }
#pragma unroll
      for (int mi = 0; mi < 4; ++mi) {
        int r = mi * 16 + l16;
        bf16x8 aF = *(const bf16x8*)&As[r * 64 + ((cc ^ (r & 7)) << 3)];
        acc[mi] = __builtin_amdgcn_mfma_f32_16x16x32_bf16(aF, bF, acc[mi], 0, 0, 0);
      }
    }
  }
#pragma unroll
  for (int mi = 0; mi < 4; ++mi) {
#pragma unroll
    for (int i = 0; i < 4; ++i) {
      int r = row0 + mi * 16 + quad * 4 + i;
      int c = col0 + wid * 16 + l16;
      if (r < M) atomicAdd(&C[(size_t)r * Nc + c], acc[mi][i]);
    }
  }
}

__global__ void k_sk_epi(const float* __restrict__ Cw, const float* __restrict__ bias,
                         const int* __restrict__ rmap, unsigned short* __restrict__ out,
                         int M, int Nc) {
  int i = blockIdx.x * blockDim.x + threadIdx.x;
  if (i >= M * Nc) return;
  int r = i / Nc, c = i - r * Nc;
  out[(size_t)rmap[r] * Nc + c] = f2bf(Cw[i] + bias[c]);
}

// ---------------- CSR build ----------------
__global__ void k_scan(int* __restrict__ deg, int* __restrict__ offs, int n) {
  __shared__ int part[1024];
  int tid = threadIdx.x;
  int per = (n + 1023) >> 10;
  int start = tid * per;
  int local = 0;
  for (int i = 0; i < per; ++i) { int idx = start + i; if (idx < n) local += deg[idx]; }
  part[tid] = local;
  __syncthreads();
  for (int off = 1; off < 1024; off <<= 1) {
    int add = (tid >= off) ? part[tid - off] : 0;
    __syncthreads();
    part[tid] += add;
    __syncthreads();
  }
  int run = (tid == 0) ? 0 : part[tid - 1];
  for (int i = 0; i < per; ++i) {
    int idx = start + i;
    if (idx < n) { offs[idx] = run; run += deg[idx]; }
  }
  if (tid == 1023) offs[n] = part[1023];
  __syncthreads();
  for (int i = tid; i < n; i += 1024) deg[i] = 0;
}

__global__ void k_fill(const int* __restrict__ src, const int* __restrict__ dst,
                       const int* __restrict__ offs, int* __restrict__ cur,
                       int* __restrict__ csr, int E) {
  int e = blockIdx.x * blockDim.x + threadIdx.x;
  if (e < E) {
    int d = dst[e];
    int slot = offs[d] + atomicAdd(&cur[d], 1);
    csr[slot] = src[e];
  }
}

// ---------------- fused softmax + aggregation (H=4, D=256, ELU, bf16 in/out) ----------------
__global__ __launch_bounds__(256) void k_agg3(const unsigned short* __restrict__ f,
                                              const float* __restrict__ el,
                                              const float* __restrict__ er,
                                              const int* __restrict__ offs,
                                              const int* __restrict__ csr,
                                              const float* __restrict__ bias,
                                              unsigned short* __restrict__ out) {
  __shared__ float xs[4][kMaxDeg];
  int v = blockIdx.x;
  int tid = threadIdx.x;
  int h = tid >> 6, lane = tid & 63;
  int e0 = offs[v];
  int deg = offs[v + 1] - e0;
  if (deg > kMaxDeg) deg = kMaxDeg;

  float erv = er[v * 4 + h];
  float m = -1e30f;
  for (int base = 0; base < deg; base += 64) {
    int idx = base + lane;
    float x = -1e30f;
    if (idx < deg) {
      int s = csr[e0 + idx];
      x = el[s * 4 + h] + erv;
      x = x > 0.f ? x : 0.2f * x;
      xs[h][idx] = x;
    }
    float mm = x;
#pragma unroll
    for (int o = 32; o; o >>= 1) mm = fmaxf(mm, __shfl_xor(mm, o));
    m = fmaxf(m, mm);
  }
  float zs = 0.f;
  for (int base = 0; base < deg; base += 64) {
    int idx = base + lane;
    if (idx < deg) {
      float w = expf(xs[h][idx] - m);
      xs[h][idx] = w;
      zs += w;
    }
  }
#pragma unroll
  for (int o = 32; o; o >>= 1) zs += __shfl_xor(zs, o);
  float rz = 1.f / zs;
  for (int base = 0; base < deg; base += 64) {
    int idx = base + lane;
    if (idx < deg) xs[h][idx] *= rz;
  }
  __syncthreads();

  int d0 = tid * 4;
  float a0 = 0.f, a1 = 0.f, a2 = 0.f, a3 = 0.f;
  for (int e = 0; e < deg; ++e) {
    int s = csr[e0 + e];
    float w = xs[h][e];
    ushort4 fv = *(const ushort4*)(f + (size_t)s * 1024 + d0);
    a0 += w * bf2f(fv.x);
    a1 += w * bf2f(fv.y);
    a2 += w * bf2f(fv.z);
    a3 += w * bf2f(fv.w);
  }
  float4 bv = *(const float4*)(bias + d0);
  float o0 = a0 + bv.x, o1 = a1 + bv.y, o2 = a2 + bv.z, o3 = a3 + bv.w;
  o0 = o0 > 0.f ? o0 : expm1f(o0);
  o1 = o1 > 0.f ? o1 : expm1f(o1);
  o2 = o2 > 0.f ? o2 : expm1f(o2);
  o3 = o3 > 0.f ? o3 : expm1f(o3);
  ushort4 ov;
  ov.x = f2bf(o0); ov.y = f2bf(o1); ov.z = f2bf(o2); ov.w = f2bf(o3);
  *(ushort4*)(out + (size_t)v * 1024 + d0) = ov;
}

// ---------------- sparse gat2 helpers ----------------
__global__ void k_rows2(const int* __restrict__ sid, const int* __restrict__ offs,
                        const int* __restrict__ csr, int* __restrict__ rowlist,
                        int* __restrict__ info) {
  __shared__ int degs[kB], starts[kB], total;
  int tid = threadIdx.x;
  int bv = tid >> 6, lane = tid & 63;
  if (tid < kB) {
    int v = sid[tid];
    degs[tid] = offs[v + 1] - offs[v];
  }
  __syncthreads();
  if (tid == 0) {
    int p = 0;
    for (int b = 0; b < kB; ++b) {
      starts[b] = p;
      int d = degs[b];
      if (p + d > kCap) d = kCap - p;
      degs[b] = d;
      p += d;
    }
    total = p;
  }
  __syncthreads();
  int v = sid[bv];
  int e0 = offs[v];
  int deg = degs[bv];
  int start = starts[bv];
  if (lane == 0) {
    info[bv] = start;
    info[4 + bv] = deg;
    info[8 + bv] = start;
  }
  __syncthreads();
  for (int idx = lane; idx < deg; idx += 64) {
    int s = csr[e0 + idx];
    rowlist[start + idx] = s;
    if (s == v) info[8 + bv] = start + idx;
  }
  for (int i = total + tid; i < kCap; i += 256) rowlist[i] = 0;
}

__global__ void k_elr_c(const float* __restrict__ fc, const float* __restrict__ al,
                        const float* __restrict__ ar, float* __restrict__ el,
                        float* __restrict__ er) {
  int r = blockIdx.x;
  int lane = threadIdx.x;
  float a = 0.f, b = 0.f;
  for (int d = lane * 4; d < 512; d += 256) {
    float4 x = *(const float4*)(fc + (size_t)r * 512 + d);
    float4 av = *(const float4*)(al + d);
    float4 rv = *(const float4*)(ar + d);
    a += x.x * av.x + x.y * av.y + x.z * av.z + x.w * av.w;
    b += x.x * rv.x + x.y * rv.y + x.z * rv.z + x.w * rv.w;
  }
#pragma unroll
  for (int off = 32; off; off >>= 1) {
    a += __shfl_down(a, off);
    b += __shfl_down(b, off);
  }
  if (lane == 0) { el[r] = a; er[r] = b; }
}

__global__ __launch_bounds__(256) void k_agg_fin2(const float* __restrict__ fc,
                                                  const float* __restrict__ el,
                                                  const float* __restrict__ er,
                                                  const int* __restrict__ info,
                                                  const float* __restrict__ bias,
                                                  float* __restrict__ out) {
  int bv = blockIdx.x;
  int tid = threadIdx.x;
  int start = info[bv], cnt = info[4 + bv];
  float erv = er[info[8 + bv]];
  float m = -1e30f;
  for (int i = 0; i < cnt; ++i) {
    float x = el[start + i] + erv;
    x = x > 0.f ? x : 0.2f * x;
    m = fmaxf(m, x);
  }
  float z = 0.f, a0 = 0.f, a1 = 0.f;
  for (int i = 0; i < cnt; ++i) {
    int r = start + i;
    float x = el[r] + erv;
    x = x > 0.f ? x : 0.2f * x;
    float w = expf(x - m);
    z += w;
    a0 += w * fc[(size_t)r * 512 + tid];
    a1 += w * fc[(size_t)r * 512 + 256 + tid];
  }
  out[bv * 512 + tid] = a0 / z + bias[tid];
  out[bv * 512 + 256 + tid] = a1 / z + bias[256 + tid];
}

// ---------------- launcher ----------------
extern "C" void kernel_launch(void* const* d_in, const int* in_sizes, int n_in,
                              void* d_out, int out_size, void* d_ws, size_t ws_size,
                              hipStream_t stream) {
  const int*   all_words   = (const int*)d_in[0];
  const float* image_feats = (const float*)d_in[1];
  const int*   sentences   = (const int*)d_in[2];
  const float* sent_mask   = (const float*)d_in[3];
  const int*   utterances  = (const int*)d_in[4];
  const float* utt_mask    = (const float*)d_in[5];
  const int*   session_ids = (const int*)d_in[6];
  const int*   edge_src    = (const int*)d_in[7];
  const int*   edge_dst    = (const int*)d_in[8];
  const float* word_embed  = (const float*)d_in[9];
  const float* text_fc_w   = (const float*)d_in[10];
  const float* text_fc_b   = (const float*)d_in[11];
  const float* image_fc_w  = (const float*)d_in[12];
  const float* image_fc_b  = (const float*)d_in[13];
  const float* gat0_fc     = (const float*)d_in[14];
  const float* gat0_al     = (const float*)d_in[15];
  const float* gat0_ar     = (const float*)d_in[16];
  const float* gat0_b      = (const float*)d_in[17];
  const float* gat1_fc     = (const float*)d_in[18];
  const float* gat1_al     = (const float*)d_in[19];
  const float* gat1_ar     = (const float*)d_in[20];
  const float* gat1_b      = (const float*)d_in[21];
  const float* gat2_fc     = (const float*)d_in[22];
  const float* gat2_al     = (const float*)d_in[23];
  const float* gat2_ar     = (const float*)d_in[24];
  const float* gat2_b      = (const float*)d_in[25];

  const int E = in_sizes[7];

  char* base = (char*)d_ws;
  size_t off = 0;
  auto alloc = [&](size_t elems, size_t esz) -> void* {
    void* p = base + off;
    off += ((elems * esz + 255) / 256) * 256;
    return p;
  };
  unsigned short* Abf   = (unsigned short*)alloc((size_t)kN * kHid, 2);
  unsigned short* fbf   = (unsigned short*)alloc((size_t)kN * kHid, 2);
  unsigned short* txtbf = (unsigned short*)alloc((size_t)kTxtRows * kEmbPad, 2);
  unsigned short* imgbf = (unsigned short*)alloc((size_t)kB * kI * 2048, 2);
  unsigned short* wtTx  = (unsigned short*)alloc((size_t)kHid * kEmbPad, 2);
  unsigned short* wtIm  = (unsigned short*)alloc((size_t)kHid * 2048, 2);
  unsigned short* wtG0  = (unsigned short*)alloc((size_t)kNcB * kHid, 2);   // extended
  unsigned short* wtG1  = (unsigned short*)alloc((size_t)kNcB * kHid, 2);   // extended
  unsigned short* wtG2  = (unsigned short*)alloc((size_t)kOut * kHid, 2);
  float* Cimg   = (float*)alloc((size_t)kB * kI * kHid, 4);
  float* Cg2    = (float*)alloc((size_t)kCap * kOut, 4);
  float* sentb  = (float*)alloc((size_t)kB * kS * kEmb, 4);
  float* uttb   = (float*)alloc((size_t)kB * kU * kEmb, 4);
  float* sessb  = (float*)alloc((size_t)kB * kEmb, 4);
  float* el     = (float*)alloc((size_t)kN * 4, 4);
  float* er     = (float*)alloc((size_t)kN * 4, 4);
  int*   offs   = (int*)alloc(kN + 1, 4);
  int*   cnt    = (int*)alloc(kN, 4);
  int*   csr    = (int*)alloc(E, 4);
  int*   rmt    = (int*)alloc(kTxtRows, 4);
  int*   rmi    = (int*)alloc(kB * kI, 4);
  int*   rowl   = (int*)alloc(kCap, 4);
  int*   info   = (int*)alloc(16, 4);
  (void)ws_size; (void)n_in; (void)out_size;

  // 1) mega prep: transposes, img cvt, sent, rowmap, zeroing (NO wal/war here)
  constexpr int kPrepBlocks = 320 + 2048 + 1024 + 1024 + 512 + 512 + 256 + 34 + 34 + 256 + 128 + 60;
  k_prep0<<<kPrepBlocks, 256, 0, stream>>>(
      text_fc_w, wtTx, image_fc_w, wtIm, gat0_fc, wtG0, gat1_fc, wtG1, gat2_fc, wtG2,
      image_feats, imgbf, sentences, sent_mask, word_embed, sentb, rmt, rmi,
      cnt, Cimg, Cg2);

  // 2) utt + sess + wal/war (parallel)
  k_utt_sess<<<kB * kU + kB + 256, 256, 0, stream>>>(
      utterances, utt_mask, sentb, uttb, sessb,
      gat0_fc, gat1_fc, gat0_al, gat0_ar, gat1_al, gat1_ar, wtG0, wtG1);

  // 3) txt gather + edge count
  k_txtcount<<<kTxtRows + (E + 255) / 256, 256, 0, stream>>>(
      all_words, word_embed, sentb, uttb, sessb, txtbf, edge_dst, cnt, E);

  // 4) scan (also re-zeros cnt)   5) fill
  k_scan<<<1, 1024, 0, stream>>>(cnt, offs, kN);
  k_fill<<<(E + 255) / 256, 256, 0, stream>>>(edge_src, edge_dst, offs, cnt, csr, E);

  auto mmGrid = [](int M, int NcB_) {
    int nrt = (M + 127) / 128;
    return 8 * (NcB_ / 128) * ((nrt + 7) / 8);
  };

  // 6) text FC
  k_mm2<true, false><<<mmGrid(kTxtRows, kHid), 256, 0, stream>>>(
      txtbf, wtTx, text_fc_b, rmt, Abf, nullptr, nullptr, kTxtRows, kEmbPad, kHid, kHid);

  // 7-8) image FC via split-K
  k_mm_sk<<<dim3(kHid / 64, kB * kI / 64, 4), 256, 0, stream>>>(
      imgbf, wtIm, nullptr, Cimg, kB * kI, 2048, kHid, 512);
  k_sk_epi<<<(kB * kI * kHid + 255) / 256, 256, 0, stream>>>(
      Cimg, image_fc_b, rmi, Abf, kB * kI, kHid);

  // 9-10) GAT layer 0 (GEMM with fused el/er cols) + aggregation
  k_mm2<true, true><<<mmGrid(kN, kNcB), 256, 0, stream>>>(
      Abf, wtG0, nullptr, nullptr, fbf, el, er, kN, kHid, kNcB, kHid);
  k_agg3<<<kN, 256, 0, stream>>>(fbf, el, er, offs, csr, gat0_b, Abf);

  // 11-12) GAT layer 1
  k_mm2<true, true><<<mmGrid(kN, kNcB), 256, 0, stream>>>(
      Abf, wtG1, nullptr, nullptr, fbf, el, er, kN, kHid, kNcB, kHid);
  k_agg3<<<kN, 256, 0, stream>>>(fbf, el, er, offs, csr, gat1_b, Abf);

  // 13-16) GAT layer 2, sparse
  k_rows2<<<1, 256, 0, stream>>>(session_ids, offs, csr, rowl, info);
  k_mm_sk<<<dim3(kOut / 64, kCap / 64, 4), 256, 0, stream>>>(
      Abf, wtG2, rowl, Cg2, kCap, kHid, kOut, 256);
  k_elr_c<<<kCap, 64, 0, stream>>>(Cg2, gat2_al, gat2_ar, el, er);
  k_agg_fin2<<<kB, 256, 0, stream>>>(Cg2, el, er, info, gat2_b, (float*)d_out);
}